// Round 6
// baseline (784.359 us; speedup 1.0000x reference)
//
#include <hip/hip_runtime.h>
#include <math.h>

typedef _Float16 half_t;
typedef _Float16 half2_t __attribute__((ext_vector_type(2)));
typedef _Float16 half8_t __attribute__((ext_vector_type(8)));
typedef union { half8_t v8; half2_t h2[4]; } H8;

#define T_ 64
#define B_ 256
#define D_ 16
#define S_ 64
#define H_ 128
#define O_ 8
#define NSTEP 63
#define NT 1024

// ws layout (halves): Wf3 [1024][128] | Wf1 [128][64] | Wf2 [128][128], row-major fp16
#define W3_OFF 0
#define W1_OFF 131072
#define W2_OFF 139264
#define WS_HALVES 155648

// AE[j] = coefficients on k[0..j] producing the NEXT stage input (j<5) or B_SOL (j==5)
__device__ constexpr float AE[6][6] = {
  {0.161f, 0.f, 0.f, 0.f, 0.f, 0.f},
  {-0.008480655492356989f, 0.335480655492357f, 0.f, 0.f, 0.f, 0.f},
  {2.8971530571054935f, -6.359448489975075f, 4.3622954328695815f, 0.f, 0.f, 0.f},
  {5.325864828439257f, -11.748883564062828f, 7.4955393428898365f, -0.09249506636175525f, 0.f, 0.f},
  {5.86145544294642f, -12.92096931784711f, 8.159367898576159f, -0.071584973281401f, -0.028269050394068383f, 0.f},
  {0.09646076681806523f, 0.01f, 0.4798896504144996f, 1.379008574103742f, -3.290069515436081f, 2.324710524099774f}
};
__device__ constexpr float CCn[6] = {0.f, 0.161f, 0.327f, 0.9f, 0.9800255409045097f, 1.f};

__device__ __forceinline__ float softplus_f(float x) {
  return fmaxf(x, 0.f) + __logf(1.f + __expf(-fabsf(x)));
}
__device__ __forceinline__ float tanh_f(float x) {
  float xc = fminf(fmaxf(x, -12.f), 12.f);
  float e = __expf(2.f * xc);
  return (e - 1.f) * __builtin_amdgcn_rcpf(e + 1.f);
}
__device__ __forceinline__ float fdot2_f(half2_t a, half2_t b, float c) {
#if __has_builtin(__builtin_amdgcn_fdot2)
  return __builtin_amdgcn_fdot2(a, b, c, false);
#else
  return c + (float)a[0] * (float)b[0] + (float)a[1] * (float)b[1];
#endif
}

// ---------------- prologue: fp32 -> fp16 weight conversion (row-major) ----------------
__global__ __launch_bounds__(256) void convert_kernel(
    const float* __restrict__ Wf1, const float* __restrict__ Wf2,
    const float* __restrict__ Wf3, half_t* __restrict__ wsh)
{
  int q = blockIdx.x * 256 + threadIdx.x;
  if (q < W1_OFF) wsh[q] = (half_t)Wf3[q];
  else if (q < W2_OFF) wsh[q] = (half_t)Wf1[q - W1_OFF];
  else if (q < WS_HALVES) wsh[q] = (half_t)Wf2[q - W2_OFF];
}

// ---------------- main kernel ----------------
// NT=1024, exactly 4 waves/EU (128-VGPR budget). Every wave works every phase:
//   h1:   o = tid>>3, K-eighth q8 = tid&7 (4 fdot2 + 3 shuffles)
//   h2:   o = tid>>3, q8 (8 fdot2 + 3 shuffles)
//   GEMV3: pair p = tid>>1, K-half kh = tid&1; lane holds Wf3 rows p and p+512
//          (K-half each, 64 VGPRs); 1 combine shuffle; 4-layer in-wave reduce.
__global__ void __launch_bounds__(NT) __attribute__((amdgpu_waves_per_eu(4, 4)))
cde_kernel_f16(
    const float* __restrict__ ts,
    const float* __restrict__ coeff_d,
    const float* __restrict__ coeff_c,
    const float* __restrict__ coeff_b,
    const float* __restrict__ coeff_a,
    const float* __restrict__ Wi1, const float* __restrict__ bi1,
    const float* __restrict__ Wi2, const float* __restrict__ bi2,
    const float* __restrict__ bf1, const float* __restrict__ bf2,
    const float* __restrict__ bf3,
    const float* __restrict__ Wr, const float* __restrict__ br,
    const half_t* __restrict__ wsh,
    float* __restrict__ out)
{
  __shared__ __align__(16) half_t syj_h[S_];
  __shared__ __align__(16) half_t sh1h[H_];
  __shared__ __align__(16) half_t sh2h[H_];
  __shared__ float syf[S_];
  __shared__ float sWr[O_ * S_];
  __shared__ float sbr[O_];
  __shared__ float sx0[D_];
  __shared__ float sini[H_];
  __shared__ float shs[T_];      // hstep per t

  const int tid = threadIdx.x;
  const int b = blockIdx.x;
  const int w = tid >> 6;
  const int l = tid & 63;

  // GEMV3 mapping
  const int p  = tid >> 1;        // row pair base: rows p and p+512
  const int kh = tid & 1;         // K-half
  const int dI = p & 15;          // d index of both owned rows
  // h1/h2 mapping
  const int o8 = tid >> 3;
  const int q8 = tid & 7;
  // reduce leader mapping: lanes {0,1,32,33} of each wave own one s each
  const bool isLeader = ((l & 30) == 0);
  const int sL = ((l & 1) ? 32 : 0) + 2 * w + ((l >> 5) & 1);

  // ---- persistent registers ----
  half2_t w3A[32], w3B[32];   // 64 VGPRs: rows p, p+512 (K-half kh)
  {
    const half8_t* pA = (const half8_t*)(wsh + W3_OFF + (size_t)p * H_ + kh * 64);
    const half8_t* pB = (const half8_t*)(wsh + W3_OFF + (size_t)(p + 512) * H_ + kh * 64);
    #pragma unroll
    for (int c = 0; c < 8; ++c) {
      H8 ua; ua.v8 = pA[c];
      H8 ub; ub.v8 = pB[c];
      #pragma unroll
      for (int q = 0; q < 4; ++q) { w3A[c * 4 + q] = ua.h2[q]; w3B[c * 4 + q] = ub.h2[q]; }
    }
  }
  const float bf3r = (kh == 0) ? bf3[p] : bf3[p + 512];   // bias of the row this lane keeps

  half2_t w1r[4];
  { H8 u; u.v8 = *(const half8_t*)(wsh + W1_OFF + o8 * S_ + q8 * 8);
    #pragma unroll
    for (int q = 0; q < 4; ++q) w1r[q] = u.h2[q]; }
  half2_t w2r[8];
  { const half8_t* p2 = (const half8_t*)(wsh + W2_OFF + o8 * H_ + q8 * 16);
    H8 u0; u0.v8 = p2[0];
    H8 u1; u1.v8 = p2[1];
    #pragma unroll
    for (int q = 0; q < 4; ++q) { w2r[q] = u0.h2[q]; w2r[4 + q] = u1.h2[q]; } }
  const float bf1r = bf1[o8];
  const float bf2r = bf2[o8];

  // ---- one-time staging + y0 ----
  if (tid < O_ * S_) sWr[tid] = Wr[tid];
  if (tid < O_) sbr[tid] = br[tid];
  if (tid < D_) sx0[tid] = coeff_a[(size_t)b * NSTEP * D_ + tid];
  if (tid < NSTEP) shs[tid] = ts[tid + 1] - ts[tid];
  __syncthreads();
  if (tid < H_) {
    float acc = bi1[tid];
    #pragma unroll
    for (int d = 0; d < D_; ++d) acc += sx0[d] * Wi1[tid * D_ + d];
    sini[tid] = softplus_f(acc);
  }
  __syncthreads();
  if (tid < S_) {
    float acc = bi2[tid];
    for (int h = 0; h < H_; ++h) acc += sini[h] * Wi2[tid * H_ + h];
    syf[tid] = acc;
  }
  __syncthreads();

  float yr = 0.f;
  float kr[6] = {0.f, 0.f, 0.f, 0.f, 0.f, 0.f};
  if (isLeader) {
    yr = syf[sL];
    syj_h[sL] = (half_t)yr;
  }
  __syncthreads();

  // ---- time loop ----
  for (int t = 0; t < NSTEP; ++t) {
    const float hstep = shs[t];
    const size_t cidx = ((size_t)b * NSTEP + t) * D_ + dI;
    const float cbv = coeff_b[cidx];
    const float ccv = coeff_c[cidx];
    const float cdv = coeff_d[cidx];

    #pragma unroll
    for (int j = 0; j < 6; ++j) {
      // ---- h1 = softplus(yj @ Wf1^T + bf1), 8-lane split-K ----
      {
        H8 a; a.v8 = *(const half8_t*)(syj_h + q8 * 8);
        float acc = 0.f;
        #pragma unroll
        for (int q = 0; q < 4; ++q) acc = fdot2_f(w1r[q], a.h2[q], acc);
        acc += __shfl_xor(acc, 1);
        acc += __shfl_xor(acc, 2);
        acc += __shfl_xor(acc, 4);
        if (q8 == 0) sh1h[o8] = (half_t)softplus_f(acc + bf1r);
      }
      __syncthreads();   // B1

      // ---- h2 = softplus(h1 @ Wf2^T + bf2), 8-lane split-K ----
      {
        const half8_t* ap = (const half8_t*)(sh1h + q8 * 16);
        H8 a0; a0.v8 = ap[0];
        H8 a1; a1.v8 = ap[1];
        float acc = 0.f;
        #pragma unroll
        for (int q = 0; q < 4; ++q) acc = fdot2_f(w2r[q], a0.h2[q], acc);
        #pragma unroll
        for (int q = 0; q < 4; ++q) acc = fdot2_f(w2r[4 + q], a1.h2[q], acc);
        acc += __shfl_xor(acc, 1);
        acc += __shfl_xor(acc, 2);
        acc += __shfl_xor(acc, 4);
        if (q8 == 0) sh2h[o8] = (half_t)softplus_f(acc + bf2r);
      }
      __syncthreads();   // B2

      // ---- GEMV3 + reduce + RK update ----
      {
        const half8_t* hp = (const half8_t*)(sh2h + kh * 64);
        float aA0 = 0.f, aA1 = 0.f, aB0 = 0.f, aB1 = 0.f;
        #pragma unroll
        for (int c = 0; c < 8; ++c) {
          H8 u; u.v8 = hp[c];
          aA0 = fdot2_f(w3A[c * 4 + 0], u.h2[0], aA0);
          aA1 = fdot2_f(w3A[c * 4 + 1], u.h2[1], aA1);
          aA0 = fdot2_f(w3A[c * 4 + 2], u.h2[2], aA0);
          aA1 = fdot2_f(w3A[c * 4 + 3], u.h2[3], aA1);
          aB0 = fdot2_f(w3B[c * 4 + 0], u.h2[0], aB0);
          aB1 = fdot2_f(w3B[c * 4 + 1], u.h2[1], aB1);
          aB0 = fdot2_f(w3B[c * 4 + 2], u.h2[2], aB0);
          aB1 = fdot2_f(w3B[c * 4 + 3], u.h2[3], aB1);
        }
        float accA = aA0 + aA1, accB = aB0 + aB1;
        // combine the two K-halves (lane pair 2p/2p+1): both lanes get full dots
        accA += __shfl_xor(accA, 1);
        accB += __shfl_xor(accB, 1);
        // even lane keeps row p, odd lane keeps row p+512
        const float dot = kh ? accB : accA;
        const float frac = CCn[j] * hstep;
        const float dx = cbv + frac * (2.f * ccv + 3.f * frac * cdv);
        float part = tanh_f(dot + bf3r) * dx;
        // reduce the 16 rows of each s (same-parity lanes, masks 2,4,8,16)
        part += __shfl_xor(part, 2);
        part += __shfl_xor(part, 4);
        part += __shfl_xor(part, 8);
        part += __shfl_xor(part, 16);
        if (isLeader) {
          kr[j] = part;
          float sacc = AE[j][0] * kr[0];
          #pragma unroll
          for (int m = 1; m < 6; ++m) if (m <= j) sacc += AE[j][m] * kr[m];
          float yn = yr + hstep * sacc;
          if (j == 5) { yr = yn; syf[sL] = yn; }
          syj_h[sL] = (half_t)yn;
        }
        // out-projection of y_t overlapped into stage-0 update phase (wave 15)
        if (w == 15 && j == 0) {
          const int oo = l >> 3, kc = l & 7;
          float a = 0.f;
          #pragma unroll
          for (int i = 0; i < 8; ++i) a += syf[kc * 8 + i] * sWr[oo * S_ + kc * 8 + i];
          a += __shfl_down(a, 4, 8);
          a += __shfl_down(a, 2, 8);
          a += __shfl_down(a, 1, 8);
          if (kc == 0) out[((size_t)b * T_ + t) * O_ + oo] = a + sbr[oo];
        }
      }
      __syncthreads();   // B3
    }
  }

  // final projection: out[b,63,:]
  if (w == 15) {
    const int oo = l >> 3, kc = l & 7;
    float a = 0.f;
    #pragma unroll
    for (int i = 0; i < 8; ++i) a += syf[kc * 8 + i] * sWr[oo * S_ + kc * 8 + i];
    a += __shfl_down(a, 4, 8);
    a += __shfl_down(a, 2, 8);
    a += __shfl_down(a, 1, 8);
    if (kc == 0) out[((size_t)b * T_ + (T_ - 1)) * O_ + oo] = a + sbr[oo];
  }
}

extern "C" void kernel_launch(void* const* d_in, const int* in_sizes, int n_in,
                              void* d_out, int out_size, void* d_ws, size_t ws_size,
                              hipStream_t stream) {
  const float* ts  = (const float*)d_in[0];
  const float* cd  = (const float*)d_in[1];
  const float* cc  = (const float*)d_in[2];
  const float* cb  = (const float*)d_in[3];
  const float* ca  = (const float*)d_in[4];
  const float* Wi1 = (const float*)d_in[5];
  const float* bi1 = (const float*)d_in[6];
  const float* Wi2 = (const float*)d_in[7];
  const float* bi2 = (const float*)d_in[8];
  const float* Wf1 = (const float*)d_in[9];
  const float* bf1 = (const float*)d_in[10];
  const float* Wf2 = (const float*)d_in[11];
  const float* bf2 = (const float*)d_in[12];
  const float* Wf3 = (const float*)d_in[13];
  const float* bf3 = (const float*)d_in[14];
  const float* Wr  = (const float*)d_in[15];
  const float* br  = (const float*)d_in[16];

  half_t* wsh = (half_t*)d_ws;
  hipLaunchKernelGGL(convert_kernel, dim3((WS_HALVES + 255) / 256), dim3(256), 0, stream,
                     Wf1, Wf2, Wf3, wsh);
  hipLaunchKernelGGL(cde_kernel_f16, dim3(B_), dim3(NT), 0, stream,
                     ts, cd, cc, cb, ca, Wi1, bi1, Wi2, bi2,
                     bf1, bf2, bf3, Wr, br, wsh, (float*)d_out);
}

// Round 7
// 575.098 us; speedup vs baseline: 1.3639x; 1.3639x over previous
//
#include <hip/hip_runtime.h>
#include <math.h>

typedef _Float16 half_t;
typedef _Float16 half8_t __attribute__((ext_vector_type(8)));
typedef float float4_t __attribute__((ext_vector_type(4)));

#define T_ 64
#define B_ 256
#define D_ 16
#define S_ 64
#define H_ 128
#define O_ 8
#define NSTEP 63
#define NT 512

// ws layout (halves): Wf3 [1024][128] | Wf1 [128][64] | Wf2 [128][128], row-major fp16
#define W3_OFF 0
#define W1_OFF 131072
#define W2_OFF 139264
#define WS_HALVES 155648

#define MFMA16(a, b, c) __builtin_amdgcn_mfma_f32_16x16x32_f16(a, b, c, 0, 0, 0)

// AE[j] = coefficients on k[0..j] producing the NEXT stage input (j<5) or B_SOL (j==5)
__device__ constexpr float AE[6][6] = {
  {0.161f, 0.f, 0.f, 0.f, 0.f, 0.f},
  {-0.008480655492356989f, 0.335480655492357f, 0.f, 0.f, 0.f, 0.f},
  {2.8971530571054935f, -6.359448489975075f, 4.3622954328695815f, 0.f, 0.f, 0.f},
  {5.325864828439257f, -11.748883564062828f, 7.4955393428898365f, -0.09249506636175525f, 0.f, 0.f},
  {5.86145544294642f, -12.92096931784711f, 8.159367898576159f, -0.071584973281401f, -0.028269050394068383f, 0.f},
  {0.09646076681806523f, 0.01f, 0.4798896504144996f, 1.379008574103742f, -3.290069515436081f, 2.324710524099774f}
};
__device__ constexpr float CCn[6] = {0.f, 0.161f, 0.327f, 0.9f, 0.9800255409045097f, 1.f};

__device__ __forceinline__ float softplus_f(float x) {
  return fmaxf(x, 0.f) + __logf(1.f + __expf(-fabsf(x)));
}
__device__ __forceinline__ float tanh_f(float x) {
  float xc = fminf(fmaxf(x, -12.f), 12.f);
  float e = __expf(2.f * xc);
  return (e - 1.f) * __builtin_amdgcn_rcpf(e + 1.f);
}

// ---------------- prologue: fp32 -> fp16 weight conversion (row-major) ----------------
__global__ __launch_bounds__(256) void convert_kernel(
    const float* __restrict__ Wf1, const float* __restrict__ Wf2,
    const float* __restrict__ Wf3, half_t* __restrict__ wsh)
{
  int q = blockIdx.x * 256 + threadIdx.x;
  if (q < W1_OFF) wsh[q] = (half_t)Wf3[q];
  else if (q < W2_OFF) wsh[q] = (half_t)Wf1[q - W1_OFF];
  else if (q < WS_HALVES) wsh[q] = (half_t)Wf2[q - W2_OFF];
}

// ---------------- main kernel: MFMA with row-replicated A, AGPR-resident B ----------------
// NT=512 (8 waves, 2/SIMD, 512-reg unified budget). Per wave:
//   h1 : B-tile n=16w..16w+15 of Wf1 (K=64, 2 MFMA)
//   h2 : B-tile of Wf2 (K=128, 4 MFMA)
//   G3 : 8 B-tiles of Wf3 (rows 128w..128w+127), 32 MFMA
// A is the activation vector replicated across rows (all lanes in a quad load the
// same K-chunk), so every lane's C reg0 holds the valid dot for col c = lane&15.
__global__ void __launch_bounds__(NT) __attribute__((amdgpu_waves_per_eu(2, 2)))
cde_kernel_mfma(
    const float* __restrict__ ts,
    const float* __restrict__ coeff_d,
    const float* __restrict__ coeff_c,
    const float* __restrict__ coeff_b,
    const float* __restrict__ coeff_a,
    const float* __restrict__ Wi1, const float* __restrict__ bi1,
    const float* __restrict__ Wi2, const float* __restrict__ bi2,
    const float* __restrict__ bf1, const float* __restrict__ bf2,
    const float* __restrict__ bf3,
    const float* __restrict__ Wr, const float* __restrict__ br,
    const half_t* __restrict__ wsh,
    float* __restrict__ out)
{
  __shared__ __align__(16) half_t syj_h[S_];
  __shared__ __align__(16) half_t sh1h[H_];
  __shared__ __align__(16) half_t sh2h[H_];
  __shared__ float syf[S_];
  __shared__ float sWr[O_ * S_];
  __shared__ float sbr[O_];
  __shared__ float sx0[D_];
  __shared__ float sini[H_];
  __shared__ float shs[T_];

  const int tid = threadIdx.x;
  const int b = blockIdx.x;
  const int w = tid >> 6;          // wave 0..7
  const int lane = tid & 63;
  const int q = lane >> 4;         // quad 0..3
  const int c = lane & 15;         // fragment column

  const half_t* __restrict__ w3p = wsh + W3_OFF;
  const half_t* __restrict__ w1p = wsh + W1_OFF;
  const half_t* __restrict__ w2p = wsh + W2_OFF;

  // ---- persistent B fragments (AGPR-resident is fine: MFMA reads them natively) ----
  const int n1 = 16 * w + c;       // output column for h1/h2 tiles
  half8_t bW1[2], bW2[4], bW3[8][4];
  #pragma unroll
  for (int ks = 0; ks < 2; ++ks)
    bW1[ks] = *(const half8_t*)(w1p + n1 * S_ + ks * 32 + q * 8);
  #pragma unroll
  for (int ks = 0; ks < 4; ++ks)
    bW2[ks] = *(const half8_t*)(w2p + n1 * H_ + ks * 32 + q * 8);
  #pragma unroll
  for (int t = 0; t < 8; ++t) {
    const int r = 16 * (8 * w + t) + c;   // Wf3 row for this tile/col
    #pragma unroll
    for (int ks = 0; ks < 4; ++ks)
      bW3[t][ks] = *(const half8_t*)(w3p + (size_t)r * H_ + ks * 32 + q * 8);
  }
  const float bf1r = bf1[n1];
  const float bf2r = bf2[n1];
  // epilogue rows this lane keeps: s0 = 8w+2q, s1 = s0+1 (col c = d)
  const int s0 = 8 * w + 2 * q;
  const float bf3r0 = bf3[16 * s0 + c];
  const float bf3r1 = bf3[16 * (s0 + 1) + c];
  const bool isLeader = (c == 0);

  // ---- one-time staging + y0 ----
  if (tid < O_ * S_) sWr[tid] = Wr[tid];
  if (tid < O_) sbr[tid] = br[tid];
  if (tid < D_) sx0[tid] = coeff_a[(size_t)b * NSTEP * D_ + tid];
  if (tid < NSTEP) shs[tid] = ts[tid + 1] - ts[tid];
  __syncthreads();
  if (tid < H_) {
    float acc = bi1[tid];
    #pragma unroll
    for (int d = 0; d < D_; ++d) acc += sx0[d] * Wi1[tid * D_ + d];
    sini[tid] = softplus_f(acc);
  }
  __syncthreads();
  if (tid < S_) {
    float acc = bi2[tid];
    for (int h = 0; h < H_; ++h) acc += sini[h] * Wi2[tid * H_ + h];
    syf[tid] = acc;
  }
  __syncthreads();

  float yr0 = 0.f, yr1 = 0.f;
  float kr0[6] = {0.f,0.f,0.f,0.f,0.f,0.f};
  float kr1[6] = {0.f,0.f,0.f,0.f,0.f,0.f};
  if (isLeader) {
    yr0 = syf[s0];
    yr1 = syf[s0 + 1];
    syj_h[s0] = (half_t)yr0;
    syj_h[s0 + 1] = (half_t)yr1;
  }
  __syncthreads();

  const float4_t Zv = {0.f, 0.f, 0.f, 0.f};

  // ---- time loop ----
  for (int t = 0; t < NSTEP; ++t) {
    const float hstep = shs[t];
    const size_t cidx = ((size_t)b * NSTEP + t) * D_ + c;
    const float cbv = coeff_b[cidx];
    const float ccv = coeff_c[cidx];
    const float cdv = coeff_d[cidx];

    #pragma unroll
    for (int j = 0; j < 6; ++j) {
      // ---- h1: yj @ Wf1^T (K=64) ----
      {
        const half8_t* ap = (const half8_t*)syj_h;
        half8_t a0 = ap[q];           // k = 0*32 + q*8 ..
        half8_t a1 = ap[4 + q];       // k = 1*32 + q*8 ..
        float4_t acc = MFMA16(a0, bW1[0], Zv);
        acc = MFMA16(a1, bW1[1], acc);
        if (q == 0) sh1h[n1] = (half_t)softplus_f(acc[0] + bf1r);
      }
      // projection of y_t overlapped here (wave 7, stage 0): syf stable until j==5
      if (w == 7 && j == 0) {
        const int oo = lane >> 3, kc = lane & 7;
        float a = 0.f;
        #pragma unroll
        for (int i = 0; i < 8; ++i) a += syf[kc * 8 + i] * sWr[oo * S_ + kc * 8 + i];
        a += __shfl_down(a, 4, 8);
        a += __shfl_down(a, 2, 8);
        a += __shfl_down(a, 1, 8);
        if (kc == 0) out[((size_t)b * T_ + t) * O_ + oo] = a + sbr[oo];
      }
      __syncthreads();   // B1

      // ---- h2: h1 @ Wf2^T (K=128) ----
      {
        const half8_t* ap = (const half8_t*)sh1h;
        half8_t a0 = ap[q], a1 = ap[4 + q], a2 = ap[8 + q], a3 = ap[12 + q];
        float4_t acc = MFMA16(a0, bW2[0], Zv);
        acc = MFMA16(a1, bW2[1], acc);
        acc = MFMA16(a2, bW2[2], acc);
        acc = MFMA16(a3, bW2[3], acc);
        if (q == 0) sh2h[n1] = (half_t)softplus_f(acc[0] + bf2r);
      }
      __syncthreads();   // B2

      // ---- GEMV3: h2 @ Wf3^T (K=128, 8 tiles) + epilogue + RK update ----
      {
        const half8_t* ap = (const half8_t*)sh2h;
        half8_t a0 = ap[q], a1 = ap[4 + q], a2 = ap[8 + q], a3 = ap[12 + q];
        float4_t acc3[8];
        #pragma unroll
        for (int tt = 0; tt < 8; ++tt) acc3[tt] = MFMA16(a0, bW3[tt][0], Zv);
        #pragma unroll
        for (int tt = 0; tt < 8; ++tt) acc3[tt] = MFMA16(a1, bW3[tt][1], acc3[tt]);
        #pragma unroll
        for (int tt = 0; tt < 8; ++tt) acc3[tt] = MFMA16(a2, bW3[tt][2], acc3[tt]);
        #pragma unroll
        for (int tt = 0; tt < 8; ++tt) acc3[tt] = MFMA16(a3, bW3[tt][3], acc3[tt]);

        // quad q consumes tiles 2q, 2q+1 (every lane's reg0 is valid for col c)
        float v0, v1;
        if (q == 0)      { v0 = acc3[0][0]; v1 = acc3[1][0]; }
        else if (q == 1) { v0 = acc3[2][0]; v1 = acc3[3][0]; }
        else if (q == 2) { v0 = acc3[4][0]; v1 = acc3[5][0]; }
        else             { v0 = acc3[6][0]; v1 = acc3[7][0]; }

        const float frac = CCn[j] * hstep;
        const float dx = cbv + frac * (2.f * ccv + 3.f * frac * cdv);
        float p0 = tanh_f(v0 + bf3r0) * dx;
        float p1 = tanh_f(v1 + bf3r1) * dx;
        // reduce over the 16 cols (=d) within the quad
        p0 += __shfl_xor(p0, 1);  p1 += __shfl_xor(p1, 1);
        p0 += __shfl_xor(p0, 2);  p1 += __shfl_xor(p1, 2);
        p0 += __shfl_xor(p0, 4);  p1 += __shfl_xor(p1, 4);
        p0 += __shfl_xor(p0, 8);  p1 += __shfl_xor(p1, 8);

        if (isLeader) {
          kr0[j] = p0;
          kr1[j] = p1;
          float sa0 = AE[j][0] * kr0[0];
          float sa1 = AE[j][0] * kr1[0];
          #pragma unroll
          for (int m = 1; m < 6; ++m) if (m <= j) { sa0 += AE[j][m] * kr0[m]; sa1 += AE[j][m] * kr1[m]; }
          float yn0 = yr0 + hstep * sa0;
          float yn1 = yr1 + hstep * sa1;
          if (j == 5) { yr0 = yn0; yr1 = yn1; syf[s0] = yn0; syf[s0 + 1] = yn1; }
          syj_h[s0] = (half_t)yn0;
          syj_h[s0 + 1] = (half_t)yn1;
        }
      }
      __syncthreads();   // B3
    }
  }

  // final projection: out[b,63,:]
  if (w == 7) {
    const int oo = lane >> 3, kc = lane & 7;
    float a = 0.f;
    #pragma unroll
    for (int i = 0; i < 8; ++i) a += syf[kc * 8 + i] * sWr[oo * S_ + kc * 8 + i];
    a += __shfl_down(a, 4, 8);
    a += __shfl_down(a, 2, 8);
    a += __shfl_down(a, 1, 8);
    if (kc == 0) out[((size_t)b * T_ + (T_ - 1)) * O_ + oo] = a + sbr[oo];
  }
}

extern "C" void kernel_launch(void* const* d_in, const int* in_sizes, int n_in,
                              void* d_out, int out_size, void* d_ws, size_t ws_size,
                              hipStream_t stream) {
  const float* ts  = (const float*)d_in[0];
  const float* cd  = (const float*)d_in[1];
  const float* cc  = (const float*)d_in[2];
  const float* cb  = (const float*)d_in[3];
  const float* ca  = (const float*)d_in[4];
  const float* Wi1 = (const float*)d_in[5];
  const float* bi1 = (const float*)d_in[6];
  const float* Wi2 = (const float*)d_in[7];
  const float* bi2 = (const float*)d_in[8];
  const float* Wf1 = (const float*)d_in[9];
  const float* bf1 = (const float*)d_in[10];
  const float* Wf2 = (const float*)d_in[11];
  const float* bf2 = (const float*)d_in[12];
  const float* Wf3 = (const float*)d_in[13];
  const float* bf3 = (const float*)d_in[14];
  const float* Wr  = (const float*)d_in[15];
  const float* br  = (const float*)d_in[16];

  half_t* wsh = (half_t*)d_ws;
  hipLaunchKernelGGL(convert_kernel, dim3((WS_HALVES + 255) / 256), dim3(256), 0, stream,
                     Wf1, Wf2, Wf3, wsh);
  hipLaunchKernelGGL(cde_kernel_mfma, dim3(B_), dim3(NT), 0, stream,
                     ts, cd, cc, cb, ca, Wi1, bi1, Wi2, bi2,
                     bf1, bf2, bf3, Wr, br, wsh, (float*)d_out);
}